// Round 14
// baseline (776.667 us; speedup 1.0000x reference)
//
#include <hip/hip_runtime.h>
#include <math.h>

// DecoderTreeLSTM round 14.
// - Prologue: packPF (Wpre+fpk) -> fill kernel running {XCD-pinned pre-GEMM,
//   emb-GEMM, Wih/Wout packing} concurrently as a 512-block task soup.
// - lstm: faster barrier poll (s_sleep 1), X-task rotation so dist blocks get
//   last task slots, pamax packed into single 8B write-through store.

#define NBLK 512
#define NTHR 512
#define OUT_COMMIT_OFF (1016 * 151)

typedef short bf16x8 __attribute__((ext_vector_type(8)));
typedef float f32x16 __attribute__((ext_vector_type(16)));

// packed fragment buffers: short-elem off = ((tile*KB + kb)*32 + row)*8 + kk
__device__ __align__(16) short g_Wih_hi[160 * 128 * 32 * 8 + 512];   // K=1024, N=5120
__device__ __align__(16) short g_Wih_lo[160 * 128 * 32 * 8 + 512];
__device__ __align__(16) short g_Wpre_hi[192 * 256 * 32 * 8 + 512];  // K=2048, N=6144
__device__ __align__(16) short g_Wpre_lo[192 * 256 * 32 * 8 + 512];
__device__ __align__(16) short g_fpk_hi[32 * 256 * 32 * 8 + 512];    // feat 1024x2048
__device__ __align__(16) short g_fpk_lo[32 * 256 * 32 * 8 + 512];
__device__ __align__(16) unsigned g_Apk_hi[128 * 128 * 32 * 4 + 256]; // parent-h rows
__device__ __align__(16) unsigned g_Apk_lo[128 * 128 * 32 * 4 + 256];
__device__ __align__(16) unsigned g_Spk_hi[128 * 128 * 32 * 4 + 256]; // self-h rows
__device__ __align__(16) unsigned g_Spk_lo[128 * 128 * 32 * 4 + 256];
__device__ __align__(16) short g_Wout_hi[5 * 128 * 32 * 8 + 512];    // Wout 1024x160(pad)
__device__ __align__(16) short g_Wout_lo[5 * 128 * 32 * 8 + 512];

__device__ __align__(16) float g_c[1024 * 1024];
__device__ __align__(16) float g_pre[1024 * 6144];
__device__ __align__(16) float g_gate[1120 * 5120];
__device__ __align__(16) float g_embG[152 * 6144];
__device__ __align__(16) float g_embpad[162 * 224];
__device__ __align__(16) float g_zero[128];
__device__ __align__(16) unsigned long long g_pamax[128 * 32 * 5 + 64]; // (idx<<32)|valbits
__device__ int g_lvl_start[1025];
__device__ int g_tile_off[1025];
__device__ int g_order[1024];
__device__ int g_prow[1024];
__device__ int g_cstart[1025];
__device__ int g_clist[1024];
__device__ int g_numlvl;
__device__ unsigned g_barcnt[512];

// ---------------- helpers ----------------
__device__ __forceinline__ unsigned short bf16_rn(float x) {
  union { float f; unsigned u; } v; v.f = x;
  unsigned r = v.u + 0x7fffu + ((v.u >> 16) & 1u);
  return (unsigned short)(r >> 16);
}
__device__ __forceinline__ float bf16_tof(unsigned short h) {
  union { float f; unsigned u; } v; v.u = ((unsigned)h) << 16; return v.f;
}
__device__ __forceinline__ void split2(float x, unsigned short& hi, unsigned short& lo) {
  hi = bf16_rn(x);
  lo = bf16_rn(x - bf16_tof(hi));
}
__device__ __forceinline__ f32x16 mfma3(bf16x8 ah, bf16x8 al, bf16x8 bh, bf16x8 bl, f32x16 c) {
  c = __builtin_amdgcn_mfma_f32_32x32x16_bf16(ah, bh, c, 0, 0, 0);
  c = __builtin_amdgcn_mfma_f32_32x32x16_bf16(ah, bl, c, 0, 0, 0);
  c = __builtin_amdgcn_mfma_f32_32x32x16_bf16(al, bh, c, 0, 0, 0);
  return c;
}

#define AST_F(p, v)  __hip_atomic_store((p), (v), __ATOMIC_RELAXED, __HIP_MEMORY_SCOPE_AGENT)
#define AST_U(p, v)  __hip_atomic_store((p), (v), __ATOMIC_RELAXED, __HIP_MEMORY_SCOPE_AGENT)

#define LD8(p, o) (*(const bf16x8*)((p) + (o)))

template<int NS>
__device__ __forceinline__ f32x16 gemm1x(const short* __restrict__ pah,
                                         const short* __restrict__ pal,
                                         const short* __restrict__ pbh,
                                         const short* __restrict__ pbl) {
  f32x16 acc = {};
  bf16x8 ahe = LD8(pah, 0),   ale = LD8(pal, 0);
  bf16x8 bhe = LD8(pbh, 0),   ble = LD8(pbl, 0);
  bf16x8 aho = LD8(pah, 512), alo = LD8(pal, 512);
  bf16x8 bho = LD8(pbh, 512), blo = LD8(pbl, 512);
  for (int g = 0; g + 1 < NS / 2; ++g) {
    const size_t o = (size_t)(2 * g + 2) * 512;
    acc = mfma3(ahe, ale, bhe, ble, acc);
    ahe = LD8(pah, o); ale = LD8(pal, o); bhe = LD8(pbh, o); ble = LD8(pbl, o);
    acc = mfma3(aho, alo, bho, blo, acc);
    aho = LD8(pah, o + 512); alo = LD8(pal, o + 512);
    bho = LD8(pbh, o + 512); blo = LD8(pbl, o + 512);
  }
  acc = mfma3(ahe, ale, bhe, ble, acc);
  acc = mfma3(aho, alo, bho, blo, acc);
  return acc;
}

template<int NS>
__device__ __forceinline__ void gemm2x(const short* __restrict__ pa0h, const short* __restrict__ pa0l,
                                       const short* __restrict__ pa1h, const short* __restrict__ pa1l,
                                       const short* __restrict__ pbh,  const short* __restrict__ pbl,
                                       f32x16& acc0, f32x16& acc1) {
  bf16x8 a0he = LD8(pa0h, 0),   a0le = LD8(pa0l, 0);
  bf16x8 a1he = LD8(pa1h, 0),   a1le = LD8(pa1l, 0);
  bf16x8 bhe  = LD8(pbh, 0),    ble  = LD8(pbl, 0);
  bf16x8 a0ho = LD8(pa0h, 512), a0lo = LD8(pa0l, 512);
  bf16x8 a1ho = LD8(pa1h, 512), a1lo = LD8(pa1l, 512);
  bf16x8 bho  = LD8(pbh, 512),  blo  = LD8(pbl, 512);
  for (int g = 0; g + 1 < NS / 2; ++g) {
    const size_t o = (size_t)(2 * g + 2) * 512;
    acc0 = mfma3(a0he, a0le, bhe, ble, acc0);
    acc1 = mfma3(a1he, a1le, bhe, ble, acc1);
    a0he = LD8(pa0h, o); a0le = LD8(pa0l, o);
    a1he = LD8(pa1h, o); a1le = LD8(pa1l, o);
    bhe = LD8(pbh, o);   ble = LD8(pbl, o);
    acc0 = mfma3(a0ho, a0lo, bho, blo, acc0);
    acc1 = mfma3(a1ho, a1lo, bho, blo, acc1);
    a0ho = LD8(pa0h, o + 512); a0lo = LD8(pa0l, o + 512);
    a1ho = LD8(pa1h, o + 512); a1lo = LD8(pa1l, o + 512);
    bho = LD8(pbh, o + 512);   blo = LD8(pbl, o + 512);
  }
  acc0 = mfma3(a0he, a0le, bhe, ble, acc0);
  acc1 = mfma3(a1he, a1le, bhe, ble, acc1);
  acc0 = mfma3(a0ho, a0lo, bho, blo, acc0);
  acc1 = mfma3(a1ho, a1lo, bho, blo, acc1);
}

__device__ __forceinline__ void gload_lds16(const float* g, float* s) {
  __builtin_amdgcn_global_load_lds(
      (const __attribute__((address_space(1))) void*)g,
      (__attribute__((address_space(3))) void*)s, 16, 0, 0);
}

__device__ __forceinline__ void gbar(unsigned int* gen) {
  __syncthreads();
  if (threadIdx.x == 0) {
    ++(*gen);
    __hip_atomic_fetch_add(&g_barcnt[((unsigned)blockIdx.x & 15) << 5], 1u,
                           __ATOMIC_RELAXED, __HIP_MEMORY_SCOPE_AGENT);
    const unsigned int target = (unsigned int)NBLK * (*gen);
    for (;;) {
      unsigned int s = 0;
      #pragma unroll
      for (int i = 0; i < 16; ++i)
        s += __hip_atomic_load(&g_barcnt[i << 5], __ATOMIC_RELAXED, __HIP_MEMORY_SCOPE_AGENT);
      if (s >= target) break;
      __builtin_amdgcn_s_sleep(1);
    }
  }
  __syncthreads();
}

__device__ __forceinline__ int pamax_combine(int prow) {
  float bv = -3.4e38f; int bi = 1;
  #pragma unroll
  for (int nt = 0; nt < 5; ++nt) {
    const unsigned long long pu = g_pamax[prow * 5 + nt];
    const float v = __uint_as_float((unsigned)pu);
    if (v > bv) { bv = v; bi = (int)(pu >> 32); }
  }
  return bi;
}

// ---------------------------------------------------------------------------
__global__ void prep_kernel(const int* __restrict__ parent,
                            const float* __restrict__ emb,
                            float* __restrict__ out) {
  __shared__ int lvl[1024];
  __shared__ int cnt[1024];
  __shared__ int c2[1024];
  __shared__ int changed;
  const int i = threadIdx.x;
  const int p = parent[i];
  lvl[i] = (p < 0) ? 0 : -1;
  for (;;) {
    if (i == 0) changed = 0;
    __syncthreads();
    if (lvl[i] < 0 && lvl[p] >= 0) { lvl[i] = lvl[p] + 1; changed = 1; }
    __syncthreads();
    const int ch = changed;
    __syncthreads();
    if (ch == 0) break;
  }
  cnt[i] = 0;
  __syncthreads();
  atomicAdd(&cnt[lvl[i]], 1);
  __syncthreads();
  if (i == 0) {
    int acc = 0, nl = 0, ta = 0;
    for (int l2 = 0; l2 < 1024; ++l2) {
      g_lvl_start[l2] = acc;
      g_tile_off[l2] = ta;
      if (cnt[l2] > 0) nl = l2 + 1;
      acc += cnt[l2];
      ta += (cnt[l2] + 31) >> 5;
    }
    g_lvl_start[1024] = acc;
    g_tile_off[1024] = ta;
    g_numlvl = nl;
  }
  __syncthreads();
  cnt[i] = 0;
  __syncthreads();
  {
    const int ni = atomicAdd(&cnt[lvl[i]], 1);
    g_order[g_lvl_start[lvl[i]] + ni] = i;
    g_prow[i] = ((g_tile_off[lvl[i]] + (ni >> 5)) << 5) | (ni & 31);
  }
  __syncthreads();
  cnt[i] = 0;
  __syncthreads();
  if (p >= 0) atomicAdd(&cnt[p], 1);
  __syncthreads();
  if (i == 0) {
    int a2 = 0;
    for (int n2 = 0; n2 < 1024; ++n2) { g_cstart[n2] = a2; a2 += cnt[n2]; }
    g_cstart[1024] = a2;
  }
  __syncthreads();
  c2[i] = 0;
  __syncthreads();
  if (p >= 0) {
    const int q = g_cstart[p] + atomicAdd(&c2[p], 1);
    g_clist[q] = i;
  }
  for (int j = i; j < 162 * 224; j += 1024) {
    const int r = j / 224, cc = j - r * 224;
    g_embpad[j] = (r < 152 && cc < 200) ? emb[r * 200 + cc] : 0.0f;
  }
  __syncthreads();
  {
    const int n0 = g_tile_off[1] * 16384;
    for (int e = i; e < n0; e += 1024) { g_Apk_hi[e] = 0u; g_Apk_lo[e] = 0u; }
  }
  if (i < 512) g_barcnt[i] = 0u;
  if (i < 128) g_zero[i] = 0.0f;
  if (i < 8) out[OUT_COMMIT_OFF + 1016 + i] = 0.0f;
}

// ---------------------------------------------------------------------------
// packPF: pack Wpre ([Wpx|Wix] rows 0..2047) and feat. (needed by fill's pre)
// ---------------------------------------------------------------------------
#define U_WPRE (192 * 256 * 32)
#define U_FEAT (32 * 256 * 32)
__global__ void packPF(const float* __restrict__ Wpx, const float* __restrict__ Wix,
                       const float* __restrict__ feat) {
  const int tot = U_WPRE + U_FEAT;
  for (int u = blockIdx.x * blockDim.x + threadIdx.x; u < tot; u += gridDim.x * blockDim.x) {
    if (u < U_WPRE) {
      const int j = u & 31, kb = (u >> 5) & 255, nt = u >> 13;
      const int n = nt * 32 + j;
      #pragma unroll
      for (int kk = 0; kk < 8; ++kk) {
        const int k = kb * 8 + kk;
        const float v = (n < 1024) ? Wpx[(size_t)k * 1024 + n]
                                   : Wix[(size_t)k * 5120 + (n - 1024)];
        unsigned short h, l; split2(v, h, l);
        g_Wpre_hi[(size_t)u * 8 + kk] = (short)h;
        g_Wpre_lo[(size_t)u * 8 + kk] = (short)l;
      }
    } else {
      const int u3 = u - U_WPRE;
      const int j = u3 & 31, kb = (u3 >> 5) & 255, mt = u3 >> 13;
      const int m = mt * 32 + j;
      #pragma unroll
      for (int kk = 0; kk < 8; ++kk) {
        unsigned short h, l;
        split2(feat[(size_t)m * 2048 + kb * 8 + kk], h, l);
        g_fpk_hi[(size_t)u3 * 8 + kk] = (short)h;
        g_fpk_lo[(size_t)u3 * 8 + kk] = (short)l;
      }
    }
  }
}

// ---------------------------------------------------------------------------
// fill: concurrent {XCD-pinned pre-GEMM pair, emb tiles, Wih/Wout pack chunks}.
// All outputs consumed by lstm_main (next dispatch) -> plain stores OK.
// ---------------------------------------------------------------------------
#define STEP(ACC, AV)                                  \
  ACC.x += AV.x * b0.x; ACC.y += AV.x * b0.y;          \
  ACC.x += AV.y * b1.x; ACC.y += AV.y * b1.y;          \
  ACC.x += AV.z * b2.x; ACC.y += AV.z * b2.y;          \
  ACC.x += AV.w * b3.x; ACC.y += AV.w * b3.y;

__device__ __forceinline__ void chunk_fma64(const float* __restrict__ Ab,
                                            const float* __restrict__ Bb,
                                            int l, float2* acc) {
  #pragma unroll
  for (int kq = 0; kq < 16; ++kq) {
    const float4 a0 = *(const float4*)(Ab + 0 * 64 + (kq << 2));
    const float4 a1 = *(const float4*)(Ab + 1 * 64 + (kq << 2));
    const float4 a2 = *(const float4*)(Ab + 2 * 64 + (kq << 2));
    const float4 a3 = *(const float4*)(Ab + 3 * 64 + (kq << 2));
    const float2 b0 = *(const float2*)(Bb + ((kq << 2) + 0) * 128 + (l << 1));
    const float2 b1 = *(const float2*)(Bb + ((kq << 2) + 1) * 128 + (l << 1));
    const float2 b2 = *(const float2*)(Bb + ((kq << 2) + 2) * 128 + (l << 1));
    const float2 b3 = *(const float2*)(Bb + ((kq << 2) + 3) * 128 + (l << 1));
    STEP(acc[0], a0) STEP(acc[1], a1) STEP(acc[2], a2) STEP(acc[3], a3)
  }
}

#define U_WIH  (160 * 128 * 32)
#define U_WOUT (5 * 128 * 32)
#define NT_EMB  240
#define NT_WIH  320
#define NT_SOUP (NT_EMB + NT_WIH + 1)

__global__ __launch_bounds__(512, 2) void fill_kernel(
    const float* __restrict__ Wpx, const float* __restrict__ Wix,
    const float* __restrict__ bpx, const float* __restrict__ bix,
    const float* __restrict__ bih, const float* __restrict__ Wih,
    const float* __restrict__ Wout) {
  __shared__ __align__(16) float smem[20480];
  const int bid = (int)blockIdx.x, tid = threadIdx.x;
  const int l = tid & 63;

  // ---- pinned pre-GEMM: waves 0-3 tile 2q, waves 4-7 tile 2q+1 ----
  {
    const int x = bid & 7, q = bid >> 3;
    if (q < 48) {
      const int sel = tid >> 8;            // 0 or 1
      const int w4 = (tid >> 6) & 3;
      const int lk = l >> 5, lj = l & 31;
      const int e = 2 * q + sel;           // [0,96) per xcd
      const int ct = x + ((e % 6) << 3);
      const int mt = e / 6;
      const size_t abase0 = ((size_t)((2 * mt) * 256 + lk) * 32 + lj) * 8;
      const size_t abase1 = abase0 + 65536;
      const int nt = ct * 4 + w4;
      const size_t bbase = ((size_t)(nt * 256 + lk) * 32 + lj) * 8;
      f32x16 acc0 = {}, acc1 = {};
      gemm2x<128>(g_fpk_hi + abase0, g_fpk_lo + abase0,
                  g_fpk_hi + abase1, g_fpk_lo + abase1,
                  g_Wpre_hi + bbase, g_Wpre_lo + bbase, acc0, acc1);
      const int colg = ct * 128 + w4 * 32 + lj;
      const int rb = mt * 64 + 4 * lk;
      #pragma unroll
      for (int reg = 0; reg < 16; ++reg) {
        const int r = rb + (reg & 3) + 8 * (reg >> 2);
        g_pre[(size_t)r * 6144 + colg] = acc0[reg];
        g_pre[(size_t)(r + 32) * 6144 + colg] = acc1[reg];
      }
    }
  }
  __syncthreads();

  // ---- task soup: emb tiles, Wih pack chunks, Wout pack ----
  for (int t = bid; t < NT_SOUP; t += 512) {
    if (t < NT_EMB) {
      // emb tile: embG = embpad @ W[2048:2248] + ALL biases (fp32 LDS GEMM)
      const int w = tid >> 6;
      const int mt = t / 48, ct = t % 48;
      const int c0 = ct << 7;
      const bool isproj = ct < 8;
      const float* W1 = isproj ? Wpx : Wix;
      const size_t N1 = isproj ? 1024 : 5120;
      const int c0x = isproj ? c0 : c0 - 1024;
      const int arow = (mt << 5) + (w << 2) + (l >> 4);
      const float* asrc = g_embpad + arow * 224 + ((l & 15) << 2);
      const int brow = (w << 3) + (l >> 5);
      const int bcol = (l & 31) << 2;

      auto STAGE = [&](int c, int buf) {
        float* base = smem + buf * 10240;
        const int kb = c << 6;
        gload_lds16(asrc + kb, base + (w << 8));
        #pragma unroll
        for (int j = 0; j < 4; ++j) {
          const int k = kb + brow + (j << 1);
          const float* srcB = (k < 200) ? (W1 + (size_t)(2048 + k) * N1 + c0x + bcol)
                                        : (g_zero + bcol);
          gload_lds16(srcB, base + 2048 + (((w << 3) + (j << 1)) << 7));
        }
      };

      float2 acc[4] = {{0.f,0.f},{0.f,0.f},{0.f,0.f},{0.f,0.f}};
      STAGE(0, 0);
      asm volatile("s_waitcnt vmcnt(0)" ::: "memory");
      __builtin_amdgcn_s_barrier();
      for (int c = 0; c < 4; ++c) {
        if (c + 1 < 4) STAGE(c + 1, (c + 1) & 1);
        const int cur = c & 1;
        chunk_fma64(smem + cur * 10240 + (w << 8), smem + cur * 10240 + 2048, l, acc);
        asm volatile("s_waitcnt vmcnt(0) lgkmcnt(0)" ::: "memory");
        __builtin_amdgcn_s_barrier();
      }
      const int cc = c0 + (l << 1);
      float2 bias;
      if (isproj) { bias.x = bpx[cc]; bias.y = bpx[cc + 1]; }
      else { bias.x = bix[cc - 1024] + bih[cc - 1024]; bias.y = bix[cc - 1023] + bih[cc - 1023]; }
      #pragma unroll
      for (int i = 0; i < 4; ++i) {
        const int r = (mt << 5) + (w << 2) + i;
        if (r < 152) {
          float2 o = { acc[i].x + bias.x, acc[i].y + bias.y };
          *(float2*)(g_embG + (size_t)r * 6144 + cc) = o;
        }
      }
    } else if (t < NT_EMB + NT_WIH) {
      // Wih pack chunk: 2048 units (4 per thread)
      const int base = (t - NT_EMB) * 2048 + (tid << 2);
      #pragma unroll
      for (int k4 = 0; k4 < 4; ++k4) {
        const int u = base + k4;
        const int j = u & 31, kb = (u >> 5) & 127, nt = u >> 12;
        const int n = nt * 32 + j;
        #pragma unroll
        for (int kk = 0; kk < 8; ++kk) {
          unsigned short h, lo;
          split2(Wih[(size_t)(kb * 8 + kk) * 5120 + n], h, lo);
          g_Wih_hi[(size_t)u * 8 + kk] = (short)h;
          g_Wih_lo[(size_t)u * 8 + kk] = (short)lo;
        }
      }
    } else {
      // Wout pack (single task)
      for (int u = tid; u < U_WOUT; u += 512) {
        const int j = u & 31, kb = (u >> 5) & 127, nt = u >> 12;
        const int col = nt * 32 + j;
        #pragma unroll
        for (int kk = 0; kk < 8; ++kk) {
          const float v = (col < 151) ? Wout[(size_t)(kb * 8 + kk) * 151 + col] : 0.f;
          unsigned short h, lo; split2(v, h, lo);
          g_Wout_hi[(size_t)u * 8 + kk] = (short)h;
          g_Wout_lo[(size_t)u * 8 + kk] = (short)lo;
        }
      }
    }
    __syncthreads();
  }
}

// ---------------------------------------------------------------------------
// dist tile (spread): 32 rows x 32 cols, K-split-8 + LDS reduce.
// ---------------------------------------------------------------------------
__device__ void dist_tile(int Lp, int mt, int nt, const float* __restrict__ bout,
                          float* __restrict__ out, int tid, int w, int l,
                          int lk, int lj, float* smem, float* sdist) {
  const int s0p = g_lvl_start[Lp];
  const int Mp = g_lvl_start[Lp + 1] - s0p;
  const int tg = g_tile_off[Lp] + mt;
  const size_t ab = (size_t)tg * 32768 + (size_t)w * 4096 + (size_t)((lk << 5) + lj) * 8;
  const size_t bb = (size_t)nt * 32768 + (size_t)w * 4096 + (size_t)((lk << 5) + lj) * 8;
  f32x16 part = gemm1x<8>((const short*)g_Spk_hi + ab, (const short*)g_Spk_lo + ab,
                          g_Wout_hi + bb, g_Wout_lo + bb);
  #pragma unroll
  for (int e = 0; e < 16; ++e) smem[((e << 3) + w) * 64 + l] = part[e];
  __syncthreads();
  const int e0 = tid >> 6, lr = tid & 63;
  #pragma unroll
  for (int h = 0; h < 2; ++h) {
    const int e = e0 + (h << 3);
    float v = 0.f;
    #pragma unroll
    for (int ww = 0; ww < 8; ++ww) v += smem[((e << 3) + ww) * 64 + lr];
    const int row = (e & 3) + ((e >> 2) << 3) + ((lr >> 5) << 2);
    const int cl = lr & 31;
    const int col = (nt << 5) + cl;
    float vb = -3.4e38f;
    if (col < 151) {
      vb = v + bout[col];
      const int m = (mt << 5) + row;
      if (m < Mp) {
        const int node = g_order[s0p + m];
        if (node >= 8) out[(size_t)(node - 8) * 151 + col] = vb;
      }
    }
    sdist[row * 33 + cl] = (col >= 151 || col == 0) ? -3.4e38f : vb;
  }
  __syncthreads();
  if (tid < 32) {
    const int m = (mt << 5) + tid;
    if (m < Mp) {
      float bv = -3.4e38f; int bi = 1;
      for (int cl = 0; cl < 32; ++cl) {
        const float v = sdist[tid * 33 + cl];
        if (v > bv) { bv = v; bi = (nt << 5) + cl; }
      }
      const unsigned long long pu =
          ((unsigned long long)(unsigned)bi << 32) | (unsigned long long)__float_as_uint(bv);
      AST_U(&g_pamax[(tg * 32 + tid) * 5 + nt], pu);
    }
  }
  __syncthreads();
}

// ---------------------------------------------------------------------------
// Main persistent kernel.
// ---------------------------------------------------------------------------
__global__ __launch_bounds__(NTHR, 2) void lstm_main(
    const int* __restrict__ parent,
    const float* __restrict__ bout,
    float* __restrict__ out) {
  __shared__ float smem[8192];
  __shared__ float sdist[1056];
  unsigned int gen = 0;
  const int tid = threadIdx.x;
  const int bid = (int)blockIdx.x;
  const int w = tid >> 6, l = tid & 63;
  const int lk = l >> 5, lj = l & 31;
  const int nl = g_numlvl;
  const int x = bid & 7;
  const int u2 = 63 - (bid >> 3);   // rotated: dist blocks (low bid) take last slots

  for (int L = 0; L < nl; ++L) {
    const int s0 = g_lvl_start[L];
    const int M  = g_lvl_start[L + 1] - s0;
    const int nmt = (M + 31) >> 5;
    const int toffL = g_tile_off[L];
    const int s0p = (L > 0) ? g_lvl_start[L - 1] : 0;
    const int Mp = (L > 0) ? (s0 - s0p) : 0;
    const int nmtp = (Mp + 31) >> 5;
    const int D = nmtp * 5;

    // -------- interval X: dist-partials(L-1) [blocks < D] + spread h-GEMM(L) ----
    if (L > 0 && bid < D) {
      dist_tile(L - 1, bid / 5, bid % 5, bout, out, tid, w, l, lk, lj, smem, sdist);
    }
    {
      const int TPX = nmt * 20;
      for (int t = u2; t < TPX; t += 64) {
        const int mt = t / 20, ci = t - (t / 20) * 20;
        const int ct = x + (ci << 3);
        const int tg = toffL + mt;
        const size_t ab = (size_t)tg * 32768 + (size_t)w * 4096 + (size_t)((lk << 5) + lj) * 8;
        const size_t bb = (size_t)ct * 32768 + (size_t)w * 4096 + (size_t)((lk << 5) + lj) * 8;
        f32x16 part = gemm1x<8>((const short*)g_Apk_hi + ab, (const short*)g_Apk_lo + ab,
                                g_Wih_hi + bb, g_Wih_lo + bb);
        #pragma unroll
        for (int e = 0; e < 16; ++e) smem[((e << 3) + w) * 64 + l] = part[e];
        __syncthreads();
        const int e0 = tid >> 6, lr = tid & 63;
        #pragma unroll
        for (int h = 0; h < 2; ++h) {
          const int e = e0 + (h << 3);
          float v = 0.f;
          #pragma unroll
          for (int ww = 0; ww < 8; ++ww) v += smem[((e << 3) + ww) * 64 + lr];
          const int row = (e & 3) + ((e >> 2) << 3) + ((lr >> 5) << 2);
          const int m = (mt << 5) + row;
          if (m < M) {
            const int col = (ct << 5) + (lr & 31);
            AST_F(&g_gate[(size_t)(s0 + m) * 5120 + col], v);
          }
        }
        __syncthreads();
      }
    }
    gbar(&gen);

    // -------- interval Y --------
    if (L > 0) {
      for (int ni2 = bid; ni2 < Mp; ni2 += NBLK) {
        const int pn = g_order[s0p + ni2];
        if (pn >= 8 && tid == 0)
          out[OUT_COMMIT_OFF + pn - 8] = (float)pamax_combine(g_prow[pn]);
      }
    }
    for (int ni = bid; ni < M; ni += NBLK) {
      const int node = g_order[s0 + ni];
      const int p = parent[node];
      const int er = (p < 0) ? 0 : pamax_combine(g_prow[p]);
      const float* gt = g_gate + (size_t)(s0 + ni) * 5120;
      const float* pre = g_pre + (size_t)node * 6144;
      const float* eg  = g_embG + (size_t)er * 6144;
      const int prow = g_prow[node];
      const size_t sbase = (size_t)(prow >> 5) * 16384 + (size_t)(prow & 31) * 4;
      const int cs = g_cstart[node], ce = g_cstart[node + 1];
      const int j = tid << 1;
      const float2 g0 = *(const float2*)(gt + j);
      const float2 g1 = *(const float2*)(gt + 1024 + j);
      const float2 g2 = *(const float2*)(gt + 2048 + j);
      const float2 g3 = *(const float2*)(gt + 3072 + j);
      const float2 g4 = *(const float2*)(gt + 4096 + j);
      const float2 p0 = *(const float2*)(pre + j);
      const float2 p1 = *(const float2*)(pre + 1024 + j);
      const float2 p2 = *(const float2*)(pre + 2048 + j);
      const float2 p3 = *(const float2*)(pre + 3072 + j);
      const float2 p4 = *(const float2*)(pre + 4096 + j);
      const float2 p5 = *(const float2*)(pre + 5120 + j);
      const float2 e0v = *(const float2*)(eg + j);
      const float2 e1 = *(const float2*)(eg + 1024 + j);
      const float2 e2 = *(const float2*)(eg + 2048 + j);
      const float2 e3 = *(const float2*)(eg + 3072 + j);
      const float2 e4 = *(const float2*)(eg + 4096 + j);
      const float2 e5 = *(const float2*)(eg + 5120 + j);
      float2 pc2 = {0.f, 0.f};
      if (p >= 0) pc2 = *(const float2*)(g_c + (size_t)p * 1024 + j);

      float cv[2], hf[2];
      #pragma unroll
      for (int e = 0; e < 2; ++e) {
        const float proj = ((e == 0) ? p0.x : p0.y) + ((e == 0) ? e0v.x : e0v.y);
        const float vi = ((e == 0) ? g0.x : g0.y) + ((e == 0) ? p1.x : p1.y) + ((e == 0) ? e1.x : e1.y);
        const float vo = ((e == 0) ? g1.x : g1.y) + ((e == 0) ? p2.x : p2.y) + ((e == 0) ? e2.x : e2.y);
        const float vf = ((e == 0) ? g2.x : g2.y) + ((e == 0) ? p3.x : p3.y) + ((e == 0) ? e3.x : e3.y);
        const float vu = ((e == 0) ? g3.x : g3.y) + ((e == 0) ? p4.x : p4.y) + ((e == 0) ? e4.x : e4.y);
        const float vr = ((e == 0) ? g4.x : g4.y) + ((e == 0) ? p5.x : p5.y) + ((e == 0) ? e5.x : e5.y);
        const float ig = 1.f / (1.f + expf(-vi));
        const float og = 1.f / (1.f + expf(-vo));
        const float fg = 1.f / (1.f + expf(-vf));
        const float rg = 1.f / (1.f + expf(-vr));
        const float ug = tanhf(vu);
        const float pc = (e == 0) ? pc2.x : pc2.y;
        const float c = ig * ug + fg * pc;
        const float h = og * tanhf(c);
        cv[e] = c;
        hf[e] = rg * h + (1.f - rg) * proj;
      }
      AST_F(&g_c[(size_t)node * 1024 + j], cv[0]);
      AST_F(&g_c[(size_t)node * 1024 + j + 1], cv[1]);
      unsigned short h0, l0, h1, l1;
      split2(hf[0], h0, l0);
      split2(hf[1], h1, l1);
      const unsigned hpk = (unsigned)h0 | ((unsigned)h1 << 16);
      const unsigned lpk = (unsigned)l0 | ((unsigned)l1 << 16);
      const size_t soff = sbase + (size_t)(j >> 3) * 128 + ((j & 7) >> 1);
      AST_U(&g_Spk_hi[soff], hpk);
      AST_U(&g_Spk_lo[soff], lpk);
      for (int ci = cs; ci < ce; ++ci) {
        const int prc = g_prow[g_clist[ci]];
        const size_t aoff = (size_t)(prc >> 5) * 16384 + (size_t)(j >> 3) * 128
                          + (size_t)(prc & 31) * 4 + ((j & 7) >> 1);
        AST_U(&g_Apk_hi[aoff], hpk);
        AST_U(&g_Apk_lo[aoff], lpk);
      }
    }
    gbar(&gen);
  }

  // -------- final level: dist + commits --------
  {
    const int Lf = nl - 1;
    const int s0f = g_lvl_start[Lf];
    const int Mf = g_lvl_start[Lf + 1] - s0f;
    const int nmtf = (Mf + 31) >> 5;
    const int Df = nmtf * 5;
    if (bid < Df) {
      dist_tile(Lf, bid / 5, bid % 5, bout, out, tid, w, l, lk, lj, smem, sdist);
    }
    gbar(&gen);
    for (int ni = bid; ni < Mf; ni += NBLK) {
      const int pn = g_order[s0f + ni];
      if (pn >= 8 && tid == 0)
        out[OUT_COMMIT_OFF + pn - 8] = (float)pamax_combine(g_prow[pn]);
    }
  }
}

extern "C" void kernel_launch(void* const* d_in, const int* in_sizes, int n_in,
                              void* d_out, int out_size, void* d_ws, size_t ws_size,
                              hipStream_t stream) {
  const float* feat   = (const float*)d_in[0];
  const int*   parent = (const int*)d_in[1];
  // d_in[2] = batch_size (8), hardcoded
  const float* Wpx  = (const float*)d_in[3];
  const float* bpx  = (const float*)d_in[4];
  const float* Wix  = (const float*)d_in[5];
  const float* bix  = (const float*)d_in[6];
  const float* Wih  = (const float*)d_in[7];
  const float* bih  = (const float*)d_in[8];
  const float* Wout = (const float*)d_in[9];
  const float* bout = (const float*)d_in[10];
  const float* emb  = (const float*)d_in[11];
  float* out = (float*)d_out;

  hipLaunchKernelGGL(prep_kernel, dim3(1), dim3(1024), 0, stream, parent, emb, out);
  hipLaunchKernelGGL(packPF, dim3(2048), dim3(256), 0, stream, Wpx, Wix, feat);
  hipLaunchKernelGGL(fill_kernel, dim3(512), dim3(512), 0, stream,
                     Wpx, Wix, bpx, bix, bih, Wih, Wout);
  hipLaunchKernelGGL(lstm_main, dim3(NBLK), dim3(NTHR), 0, stream,
                     parent, bout, out);
}

// Round 15
// 623.728 us; speedup vs baseline: 1.2452x; 1.2452x over previous
//
#include <hip/hip_runtime.h>
#include <math.h>

// DecoderTreeLSTM round 15: R13 prologue structure (separate pack_all / emb_gemm /
// pre_gemm dispatches — R14's fusion serialized and regressed) + R14's lstm_main
// (sleep(1) poll, rotated X-tasks, packed pamax) + XCD-pinned pre_gemm ct.

#define NBLK 512
#define NTHR 512
#define OUT_COMMIT_OFF (1016 * 151)

typedef short bf16x8 __attribute__((ext_vector_type(8)));
typedef float f32x16 __attribute__((ext_vector_type(16)));

// packed fragment buffers: short-elem off = ((tile*KB + kb)*32 + row)*8 + kk
__device__ __align__(16) short g_Wih_hi[160 * 128 * 32 * 8 + 512];   // K=1024, N=5120
__device__ __align__(16) short g_Wih_lo[160 * 128 * 32 * 8 + 512];
__device__ __align__(16) short g_Wpre_hi[192 * 256 * 32 * 8 + 512];  // K=2048, N=6144
__device__ __align__(16) short g_Wpre_lo[192 * 256 * 32 * 8 + 512];
__device__ __align__(16) short g_fpk_hi[32 * 256 * 32 * 8 + 512];    // feat 1024x2048
__device__ __align__(16) short g_fpk_lo[32 * 256 * 32 * 8 + 512];
__device__ __align__(16) unsigned g_Apk_hi[128 * 128 * 32 * 4 + 256]; // parent-h rows
__device__ __align__(16) unsigned g_Apk_lo[128 * 128 * 32 * 4 + 256];
__device__ __align__(16) unsigned g_Spk_hi[128 * 128 * 32 * 4 + 256]; // self-h rows
__device__ __align__(16) unsigned g_Spk_lo[128 * 128 * 32 * 4 + 256];
__device__ __align__(16) short g_Wout_hi[5 * 128 * 32 * 8 + 512];    // Wout 1024x160(pad)
__device__ __align__(16) short g_Wout_lo[5 * 128 * 32 * 8 + 512];

__device__ __align__(16) float g_c[1024 * 1024];
__device__ __align__(16) float g_pre[1024 * 6144];
__device__ __align__(16) float g_gate[1120 * 5120];
__device__ __align__(16) float g_embG[152 * 6144];
__device__ __align__(16) float g_embpad[162 * 224];
__device__ __align__(16) float g_zero[128];
__device__ __align__(16) unsigned long long g_pamax[128 * 32 * 5 + 64]; // (idx<<32)|valbits
__device__ int g_lvl_start[1025];
__device__ int g_tile_off[1025];
__device__ int g_order[1024];
__device__ int g_prow[1024];
__device__ int g_cstart[1025];
__device__ int g_clist[1024];
__device__ int g_numlvl;
__device__ unsigned g_barcnt[512];

// ---------------- helpers ----------------
__device__ __forceinline__ unsigned short bf16_rn(float x) {
  union { float f; unsigned u; } v; v.f = x;
  unsigned r = v.u + 0x7fffu + ((v.u >> 16) & 1u);
  return (unsigned short)(r >> 16);
}
__device__ __forceinline__ float bf16_tof(unsigned short h) {
  union { float f; unsigned u; } v; v.u = ((unsigned)h) << 16; return v.f;
}
__device__ __forceinline__ void split2(float x, unsigned short& hi, unsigned short& lo) {
  hi = bf16_rn(x);
  lo = bf16_rn(x - bf16_tof(hi));
}
__device__ __forceinline__ f32x16 mfma3(bf16x8 ah, bf16x8 al, bf16x8 bh, bf16x8 bl, f32x16 c) {
  c = __builtin_amdgcn_mfma_f32_32x32x16_bf16(ah, bh, c, 0, 0, 0);
  c = __builtin_amdgcn_mfma_f32_32x32x16_bf16(ah, bl, c, 0, 0, 0);
  c = __builtin_amdgcn_mfma_f32_32x32x16_bf16(al, bh, c, 0, 0, 0);
  return c;
}

#define AST_F(p, v)  __hip_atomic_store((p), (v), __ATOMIC_RELAXED, __HIP_MEMORY_SCOPE_AGENT)
#define AST_U(p, v)  __hip_atomic_store((p), (v), __ATOMIC_RELAXED, __HIP_MEMORY_SCOPE_AGENT)

#define LD8(p, o) (*(const bf16x8*)((p) + (o)))

template<int NS>
__device__ __forceinline__ f32x16 gemm1x(const short* __restrict__ pah,
                                         const short* __restrict__ pal,
                                         const short* __restrict__ pbh,
                                         const short* __restrict__ pbl) {
  f32x16 acc = {};
  bf16x8 ahe = LD8(pah, 0),   ale = LD8(pal, 0);
  bf16x8 bhe = LD8(pbh, 0),   ble = LD8(pbl, 0);
  bf16x8 aho = LD8(pah, 512), alo = LD8(pal, 512);
  bf16x8 bho = LD8(pbh, 512), blo = LD8(pbl, 512);
  for (int g = 0; g + 1 < NS / 2; ++g) {
    const size_t o = (size_t)(2 * g + 2) * 512;
    acc = mfma3(ahe, ale, bhe, ble, acc);
    ahe = LD8(pah, o); ale = LD8(pal, o); bhe = LD8(pbh, o); ble = LD8(pbl, o);
    acc = mfma3(aho, alo, bho, blo, acc);
    aho = LD8(pah, o + 512); alo = LD8(pal, o + 512);
    bho = LD8(pbh, o + 512); blo = LD8(pbl, o + 512);
  }
  acc = mfma3(ahe, ale, bhe, ble, acc);
  acc = mfma3(aho, alo, bho, blo, acc);
  return acc;
}

template<int NS>
__device__ __forceinline__ void gemm2x(const short* __restrict__ pa0h, const short* __restrict__ pa0l,
                                       const short* __restrict__ pa1h, const short* __restrict__ pa1l,
                                       const short* __restrict__ pbh,  const short* __restrict__ pbl,
                                       f32x16& acc0, f32x16& acc1) {
  bf16x8 a0he = LD8(pa0h, 0),   a0le = LD8(pa0l, 0);
  bf16x8 a1he = LD8(pa1h, 0),   a1le = LD8(pa1l, 0);
  bf16x8 bhe  = LD8(pbh, 0),    ble  = LD8(pbl, 0);
  bf16x8 a0ho = LD8(pa0h, 512), a0lo = LD8(pa0l, 512);
  bf16x8 a1ho = LD8(pa1h, 512), a1lo = LD8(pa1l, 512);
  bf16x8 bho  = LD8(pbh, 512),  blo  = LD8(pbl, 512);
  for (int g = 0; g + 1 < NS / 2; ++g) {
    const size_t o = (size_t)(2 * g + 2) * 512;
    acc0 = mfma3(a0he, a0le, bhe, ble, acc0);
    acc1 = mfma3(a1he, a1le, bhe, ble, acc1);
    a0he = LD8(pa0h, o); a0le = LD8(pa0l, o);
    a1he = LD8(pa1h, o); a1le = LD8(pa1l, o);
    bhe = LD8(pbh, o);   ble = LD8(pbl, o);
    acc0 = mfma3(a0ho, a0lo, bho, blo, acc0);
    acc1 = mfma3(a1ho, a1lo, bho, blo, acc1);
    a0ho = LD8(pa0h, o + 512); a0lo = LD8(pa0l, o + 512);
    a1ho = LD8(pa1h, o + 512); a1lo = LD8(pa1l, o + 512);
    bho = LD8(pbh, o + 512);   blo = LD8(pbl, o + 512);
  }
  acc0 = mfma3(a0he, a0le, bhe, ble, acc0);
  acc1 = mfma3(a1he, a1le, bhe, ble, acc1);
  acc0 = mfma3(a0ho, a0lo, bho, blo, acc0);
  acc1 = mfma3(a1ho, a1lo, bho, blo, acc1);
}

__device__ __forceinline__ void gload_lds16(const float* g, float* s) {
  __builtin_amdgcn_global_load_lds(
      (const __attribute__((address_space(1))) void*)g,
      (__attribute__((address_space(3))) void*)s, 16, 0, 0);
}

__device__ __forceinline__ void gbar(unsigned int* gen) {
  __syncthreads();
  if (threadIdx.x == 0) {
    ++(*gen);
    __hip_atomic_fetch_add(&g_barcnt[((unsigned)blockIdx.x & 15) << 5], 1u,
                           __ATOMIC_RELAXED, __HIP_MEMORY_SCOPE_AGENT);
    const unsigned int target = (unsigned int)NBLK * (*gen);
    for (;;) {
      unsigned int s = 0;
      #pragma unroll
      for (int i = 0; i < 16; ++i)
        s += __hip_atomic_load(&g_barcnt[i << 5], __ATOMIC_RELAXED, __HIP_MEMORY_SCOPE_AGENT);
      if (s >= target) break;
      __builtin_amdgcn_s_sleep(1);
    }
  }
  __syncthreads();
}

__device__ __forceinline__ int pamax_combine(int prow) {
  float bv = -3.4e38f; int bi = 1;
  #pragma unroll
  for (int nt = 0; nt < 5; ++nt) {
    const unsigned long long pu = g_pamax[prow * 5 + nt];
    const float v = __uint_as_float((unsigned)pu);
    if (v > bv) { bv = v; bi = (int)(pu >> 32); }
  }
  return bi;
}

// ---------------------------------------------------------------------------
__global__ void prep_kernel(const int* __restrict__ parent,
                            const float* __restrict__ emb,
                            float* __restrict__ out) {
  __shared__ int lvl[1024];
  __shared__ int cnt[1024];
  __shared__ int c2[1024];
  __shared__ int changed;
  const int i = threadIdx.x;
  const int p = parent[i];
  lvl[i] = (p < 0) ? 0 : -1;
  for (;;) {
    if (i == 0) changed = 0;
    __syncthreads();
    if (lvl[i] < 0 && lvl[p] >= 0) { lvl[i] = lvl[p] + 1; changed = 1; }
    __syncthreads();
    const int ch = changed;
    __syncthreads();
    if (ch == 0) break;
  }
  cnt[i] = 0;
  __syncthreads();
  atomicAdd(&cnt[lvl[i]], 1);
  __syncthreads();
  if (i == 0) {
    int acc = 0, nl = 0, ta = 0;
    for (int l2 = 0; l2 < 1024; ++l2) {
      g_lvl_start[l2] = acc;
      g_tile_off[l2] = ta;
      if (cnt[l2] > 0) nl = l2 + 1;
      acc += cnt[l2];
      ta += (cnt[l2] + 31) >> 5;
    }
    g_lvl_start[1024] = acc;
    g_tile_off[1024] = ta;
    g_numlvl = nl;
  }
  __syncthreads();
  cnt[i] = 0;
  __syncthreads();
  {
    const int ni = atomicAdd(&cnt[lvl[i]], 1);
    g_order[g_lvl_start[lvl[i]] + ni] = i;
    g_prow[i] = ((g_tile_off[lvl[i]] + (ni >> 5)) << 5) | (ni & 31);
  }
  __syncthreads();
  cnt[i] = 0;
  __syncthreads();
  if (p >= 0) atomicAdd(&cnt[p], 1);
  __syncthreads();
  if (i == 0) {
    int a2 = 0;
    for (int n2 = 0; n2 < 1024; ++n2) { g_cstart[n2] = a2; a2 += cnt[n2]; }
    g_cstart[1024] = a2;
  }
  __syncthreads();
  c2[i] = 0;
  __syncthreads();
  if (p >= 0) {
    const int q = g_cstart[p] + atomicAdd(&c2[p], 1);
    g_clist[q] = i;
  }
  for (int j = i; j < 162 * 224; j += 1024) {
    const int r = j / 224, cc = j - r * 224;
    g_embpad[j] = (r < 152 && cc < 200) ? emb[r * 200 + cc] : 0.0f;
  }
  __syncthreads();
  {
    const int n0 = g_tile_off[1] * 16384;
    for (int e = i; e < n0; e += 1024) { g_Apk_hi[e] = 0u; g_Apk_lo[e] = 0u; }
  }
  if (i < 512) g_barcnt[i] = 0u;
  if (i < 128) g_zero[i] = 0.0f;
  if (i < 8) out[OUT_COMMIT_OFF + 1016 + i] = 0.0f;
}

// ---------------------------------------------------------------------------
// pack_all: hi/lo bf16 frag packing of Wih, [Wpx|Wix] rows 0..2047, feat, Wout.
// ---------------------------------------------------------------------------
#define U_WIH  (160 * 128 * 32)
#define U_WPRE (192 * 256 * 32)
#define U_FEAT (32 * 256 * 32)
#define U_WOUT (5 * 128 * 32)
__global__ void pack_all(const float* __restrict__ Wpx, const float* __restrict__ Wix,
                         const float* __restrict__ Wih, const float* __restrict__ feat,
                         const float* __restrict__ Wout) {
  const int tot = U_WIH + U_WPRE + U_FEAT + U_WOUT;
  for (int u = blockIdx.x * blockDim.x + threadIdx.x; u < tot; u += gridDim.x * blockDim.x) {
    if (u < U_WIH) {
      const int j = u & 31, kb = (u >> 5) & 127, nt = u >> 12;
      const int n = nt * 32 + j;
      #pragma unroll
      for (int kk = 0; kk < 8; ++kk) {
        unsigned short h, l;
        split2(Wih[(size_t)(kb * 8 + kk) * 5120 + n], h, l);
        g_Wih_hi[(size_t)u * 8 + kk] = (short)h;
        g_Wih_lo[(size_t)u * 8 + kk] = (short)l;
      }
    } else if (u < U_WIH + U_WPRE) {
      const int u2 = u - U_WIH;
      const int j = u2 & 31, kb = (u2 >> 5) & 255, nt = u2 >> 13;
      const int n = nt * 32 + j;
      #pragma unroll
      for (int kk = 0; kk < 8; ++kk) {
        const int k = kb * 8 + kk;
        const float v = (n < 1024) ? Wpx[(size_t)k * 1024 + n]
                                   : Wix[(size_t)k * 5120 + (n - 1024)];
        unsigned short h, l; split2(v, h, l);
        g_Wpre_hi[(size_t)u2 * 8 + kk] = (short)h;
        g_Wpre_lo[(size_t)u2 * 8 + kk] = (short)l;
      }
    } else if (u < U_WIH + U_WPRE + U_FEAT) {
      const int u3 = u - U_WIH - U_WPRE;
      const int j = u3 & 31, kb = (u3 >> 5) & 255, mt = u3 >> 13;
      const int m = mt * 32 + j;
      #pragma unroll
      for (int kk = 0; kk < 8; ++kk) {
        unsigned short h, l;
        split2(feat[(size_t)m * 2048 + kb * 8 + kk], h, l);
        g_fpk_hi[(size_t)u3 * 8 + kk] = (short)h;
        g_fpk_lo[(size_t)u3 * 8 + kk] = (short)l;
      }
    } else {
      const int u4 = u - U_WIH - U_WPRE - U_FEAT;
      const int j = u4 & 31, kb = (u4 >> 5) & 127, nt = u4 >> 12;
      const int col = nt * 32 + j;
      #pragma unroll
      for (int kk = 0; kk < 8; ++kk) {
        const float v = (col < 151) ? Wout[(size_t)(kb * 8 + kk) * 151 + col] : 0.f;
        unsigned short h, l; split2(v, h, l);
        g_Wout_hi[(size_t)u4 * 8 + kk] = (short)h;
        g_Wout_lo[(size_t)u4 * 8 + kk] = (short)l;
      }
    }
  }
}

// ---------------------------------------------------------------------------
// emb_gemm (fp32, proven)
// ---------------------------------------------------------------------------
#define STEP(ACC, AV)                                  \
  ACC.x += AV.x * b0.x; ACC.y += AV.x * b0.y;          \
  ACC.x += AV.y * b1.x; ACC.y += AV.y * b1.y;          \
  ACC.x += AV.z * b2.x; ACC.y += AV.z * b2.y;          \
  ACC.x += AV.w * b3.x; ACC.y += AV.w * b3.y;

__device__ __forceinline__ void chunk_fma64(const float* __restrict__ Ab,
                                            const float* __restrict__ Bb,
                                            int l, float2* acc) {
  #pragma unroll
  for (int kq = 0; kq < 16; ++kq) {
    const float4 a0 = *(const float4*)(Ab + 0 * 64 + (kq << 2));
    const float4 a1 = *(const float4*)(Ab + 1 * 64 + (kq << 2));
    const float4 a2 = *(const float4*)(Ab + 2 * 64 + (kq << 2));
    const float4 a3 = *(const float4*)(Ab + 3 * 64 + (kq << 2));
    const float2 b0 = *(const float2*)(Bb + ((kq << 2) + 0) * 128 + (l << 1));
    const float2 b1 = *(const float2*)(Bb + ((kq << 2) + 1) * 128 + (l << 1));
    const float2 b2 = *(const float2*)(Bb + ((kq << 2) + 2) * 128 + (l << 1));
    const float2 b3 = *(const float2*)(Bb + ((kq << 2) + 3) * 128 + (l << 1));
    STEP(acc[0], a0) STEP(acc[1], a1) STEP(acc[2], a2) STEP(acc[3], a3)
  }
}

__global__ __launch_bounds__(512, 2) void emb_gemm(
    const float* __restrict__ Wpx, const float* __restrict__ Wix,
    const float* __restrict__ bpx, const float* __restrict__ bix,
    const float* __restrict__ bih) {
  __shared__ __align__(16) float smem[20480];
  const int tid = threadIdx.x, w = tid >> 6, l = tid & 63;
  const int mt = blockIdx.x / 48, ct = blockIdx.x % 48;
  const int c0 = ct << 7;
  const bool isproj = ct < 8;
  const float* W1 = isproj ? Wpx : Wix;
  const size_t N1 = isproj ? 1024 : 5120;
  const int c0x = isproj ? c0 : c0 - 1024;
  const int arow = (mt << 5) + (w << 2) + (l >> 4);
  const float* asrc = g_embpad + arow * 224 + ((l & 15) << 2);
  const int brow = (w << 3) + (l >> 5);
  const int bcol = (l & 31) << 2;

  auto STAGE = [&](int c, int buf) {
    float* base = smem + buf * 10240;
    const int kb = c << 6;
    gload_lds16(asrc + kb, base + (w << 8));
    #pragma unroll
    for (int j = 0; j < 4; ++j) {
      const int k = kb + brow + (j << 1);
      const float* srcB = (k < 200) ? (W1 + (size_t)(2048 + k) * N1 + c0x + bcol)
                                    : (g_zero + bcol);
      gload_lds16(srcB, base + 2048 + (((w << 3) + (j << 1)) << 7));
    }
  };

  float2 acc[4] = {{0.f,0.f},{0.f,0.f},{0.f,0.f},{0.f,0.f}};
  STAGE(0, 0);
  asm volatile("s_waitcnt vmcnt(0)" ::: "memory");
  __builtin_amdgcn_s_barrier();
  for (int c = 0; c < 4; ++c) {
    if (c + 1 < 4) STAGE(c + 1, (c + 1) & 1);
    const int cur = c & 1;
    chunk_fma64(smem + cur * 10240 + (w << 8), smem + cur * 10240 + 2048, l, acc);
    asm volatile("s_waitcnt vmcnt(0) lgkmcnt(0)" ::: "memory");
    __builtin_amdgcn_s_barrier();
  }
  const int cc = c0 + (l << 1);
  float2 bias;
  if (isproj) { bias.x = bpx[cc]; bias.y = bpx[cc + 1]; }
  else { bias.x = bix[cc - 1024] + bih[cc - 1024]; bias.y = bix[cc - 1023] + bih[cc - 1023]; }
  #pragma unroll
  for (int i = 0; i < 4; ++i) {
    const int r = (mt << 5) + (w << 2) + i;
    if (r < 152) {
      float2 o = { acc[i].x + bias.x, acc[i].y + bias.y };
      *(float2*)(g_embG + (size_t)r * 6144 + cc) = o;
    }
  }
}

// ---------------------------------------------------------------------------
// pre_gemm (MFMA): 768 blocks, XCD-pinned ct (bid%8 -> xcd; 6 ct panels/xcd
// stay L2-resident across their 16 mt re-reads).
// ---------------------------------------------------------------------------
__global__ __launch_bounds__(256, 2) void pre_gemm_mfma() {
  const int tid = threadIdx.x, w = tid >> 6, l = tid & 63;
  const int bid = (int)blockIdx.x;
  const int x = bid & 7, e = bid >> 3;        // e in [0,96)
  const int ct = x + ((e % 6) << 3);          // pinned: 6 col-tiles per xcd
  const int mt = e / 6;                       // 16 row-tiles of 64
  const int lk = l >> 5, lj = l & 31;
  const size_t abase0 = ((size_t)((2 * mt) * 256 + lk) * 32 + lj) * 8;
  const size_t abase1 = abase0 + 65536;
  const int nt = ct * 4 + w;
  const size_t bbase = ((size_t)(nt * 256 + lk) * 32 + lj) * 8;
  f32x16 acc0 = {}, acc1 = {};
  gemm2x<128>(g_fpk_hi + abase0, g_fpk_lo + abase0,
              g_fpk_hi + abase1, g_fpk_lo + abase1,
              g_Wpre_hi + bbase, g_Wpre_lo + bbase, acc0, acc1);
  const int colg = ct * 128 + w * 32 + lj;
  const int rb = mt * 64 + 4 * lk;
  #pragma unroll
  for (int reg = 0; reg < 16; ++reg) {
    const int r = rb + (reg & 3) + 8 * (reg >> 2);
    g_pre[(size_t)r * 6144 + colg] = acc0[reg];
    g_pre[(size_t)(r + 32) * 6144 + colg] = acc1[reg];
  }
}

// ---------------------------------------------------------------------------
// dist tile (spread): 32 rows x 32 cols, K-split-8 + LDS reduce.
// ---------------------------------------------------------------------------
__device__ void dist_tile(int Lp, int mt, int nt, const float* __restrict__ bout,
                          float* __restrict__ out, int tid, int w, int l,
                          int lk, int lj, float* smem, float* sdist) {
  const int s0p = g_lvl_start[Lp];
  const int Mp = g_lvl_start[Lp + 1] - s0p;
  const int tg = g_tile_off[Lp] + mt;
  const size_t ab = (size_t)tg * 32768 + (size_t)w * 4096 + (size_t)((lk << 5) + lj) * 8;
  const size_t bb = (size_t)nt * 32768 + (size_t)w * 4096 + (size_t)((lk << 5) + lj) * 8;
  f32x16 part = gemm1x<8>((const short*)g_Spk_hi + ab, (const short*)g_Spk_lo + ab,
                          g_Wout_hi + bb, g_Wout_lo + bb);
  #pragma unroll
  for (int e = 0; e < 16; ++e) smem[((e << 3) + w) * 64 + l] = part[e];
  __syncthreads();
  const int e0 = tid >> 6, lr = tid & 63;
  #pragma unroll
  for (int h = 0; h < 2; ++h) {
    const int e = e0 + (h << 3);
    float v = 0.f;
    #pragma unroll
    for (int ww = 0; ww < 8; ++ww) v += smem[((e << 3) + ww) * 64 + lr];
    const int row = (e & 3) + ((e >> 2) << 3) + ((lr >> 5) << 2);
    const int cl = lr & 31;
    const int col = (nt << 5) + cl;
    float vb = -3.4e38f;
    if (col < 151) {
      vb = v + bout[col];
      const int m = (mt << 5) + row;
      if (m < Mp) {
        const int node = g_order[s0p + m];
        if (node >= 8) out[(size_t)(node - 8) * 151 + col] = vb;
      }
    }
    sdist[row * 33 + cl] = (col >= 151 || col == 0) ? -3.4e38f : vb;
  }
  __syncthreads();
  if (tid < 32) {
    const int m = (mt << 5) + tid;
    if (m < Mp) {
      float bv = -3.4e38f; int bi = 1;
      for (int cl = 0; cl < 32; ++cl) {
        const float v = sdist[tid * 33 + cl];
        if (v > bv) { bv = v; bi = (nt << 5) + cl; }
      }
      const unsigned long long pu =
          ((unsigned long long)(unsigned)bi << 32) | (unsigned long long)__float_as_uint(bv);
      AST_U(&g_pamax[(tg * 32 + tid) * 5 + nt], pu);
    }
  }
  __syncthreads();
}

// ---------------------------------------------------------------------------
// Main persistent kernel.
// ---------------------------------------------------------------------------
__global__ __launch_bounds__(NTHR, 2) void lstm_main(
    const int* __restrict__ parent,
    const float* __restrict__ bout,
    float* __restrict__ out) {
  __shared__ float smem[8192];
  __shared__ float sdist[1056];
  unsigned int gen = 0;
  const int tid = threadIdx.x;
  const int bid = (int)blockIdx.x;
  const int w = tid >> 6, l = tid & 63;
  const int lk = l >> 5, lj = l & 31;
  const int nl = g_numlvl;
  const int x = bid & 7;
  const int u2 = 63 - (bid >> 3);   // rotated: dist blocks (low bid) take last slots

  for (int L = 0; L < nl; ++L) {
    const int s0 = g_lvl_start[L];
    const int M  = g_lvl_start[L + 1] - s0;
    const int nmt = (M + 31) >> 5;
    const int toffL = g_tile_off[L];
    const int s0p = (L > 0) ? g_lvl_start[L - 1] : 0;
    const int Mp = (L > 0) ? (s0 - s0p) : 0;
    const int nmtp = (Mp + 31) >> 5;
    const int D = nmtp * 5;

    // -------- interval X: dist-partials(L-1) [blocks < D] + spread h-GEMM(L) ----
    if (L > 0 && bid < D) {
      dist_tile(L - 1, bid / 5, bid % 5, bout, out, tid, w, l, lk, lj, smem, sdist);
    }
    {
      const int TPX = nmt * 20;
      for (int t = u2; t < TPX; t += 64) {
        const int mt = t / 20, ci = t - (t / 20) * 20;
        const int ct = x + (ci << 3);
        const int tg = toffL + mt;
        const size_t ab = (size_t)tg * 32768 + (size_t)w * 4096 + (size_t)((lk << 5) + lj) * 8;
        const size_t bb = (size_t)ct * 32768 + (size_t)w * 4096 + (size_t)((lk << 5) + lj) * 8;
        f32x16 part = gemm1x<8>((const short*)g_Apk_hi + ab, (const short*)g_Apk_lo + ab,
                                g_Wih_hi + bb, g_Wih_lo + bb);
        #pragma unroll
        for (int e = 0; e < 16; ++e) smem[((e << 3) + w) * 64 + l] = part[e];
        __syncthreads();
        const int e0 = tid >> 6, lr = tid & 63;
        #pragma unroll
        for (int h = 0; h < 2; ++h) {
          const int e = e0 + (h << 3);
          float v = 0.f;
          #pragma unroll
          for (int ww = 0; ww < 8; ++ww) v += smem[((e << 3) + ww) * 64 + lr];
          const int row = (e & 3) + ((e >> 2) << 3) + ((lr >> 5) << 2);
          const int m = (mt << 5) + row;
          if (m < M) {
            const int col = (ct << 5) + (lr & 31);
            AST_F(&g_gate[(size_t)(s0 + m) * 5120 + col], v);
          }
        }
        __syncthreads();
      }
    }
    gbar(&gen);

    // -------- interval Y --------
    if (L > 0) {
      for (int ni2 = bid; ni2 < Mp; ni2 += NBLK) {
        const int pn = g_order[s0p + ni2];
        if (pn >= 8 && tid == 0)
          out[OUT_COMMIT_OFF + pn - 8] = (float)pamax_combine(g_prow[pn]);
      }
    }
    for (int ni = bid; ni < M; ni += NBLK) {
      const int node = g_order[s0 + ni];
      const int p = parent[node];
      const int er = (p < 0) ? 0 : pamax_combine(g_prow[p]);
      const float* gt = g_gate + (size_t)(s0 + ni) * 5120;
      const float* pre = g_pre + (size_t)node * 6144;
      const float* eg  = g_embG + (size_t)er * 6144;
      const int prow = g_prow[node];
      const size_t sbase = (size_t)(prow >> 5) * 16384 + (size_t)(prow & 31) * 4;
      const int cs = g_cstart[node], ce = g_cstart[node + 1];
      const int j = tid << 1;
      const float2 g0 = *(const float2*)(gt + j);
      const float2 g1 = *(const float2*)(gt + 1024 + j);
      const float2 g2 = *(const float2*)(gt + 2048 + j);
      const float2 g3 = *(const float2*)(gt + 3072 + j);
      const float2 g4 = *(const float2*)(gt + 4096 + j);
      const float2 p0 = *(const float2*)(pre + j);
      const float2 p1 = *(const float2*)(pre + 1024 + j);
      const float2 p2 = *(const float2*)(pre + 2048 + j);
      const float2 p3 = *(const float2*)(pre + 3072 + j);
      const float2 p4 = *(const float2*)(pre + 4096 + j);
      const float2 p5 = *(const float2*)(pre + 5120 + j);
      const float2 e0v = *(const float2*)(eg + j);
      const float2 e1 = *(const float2*)(eg + 1024 + j);
      const float2 e2 = *(const float2*)(eg + 2048 + j);
      const float2 e3 = *(const float2*)(eg + 3072 + j);
      const float2 e4 = *(const float2*)(eg + 4096 + j);
      const float2 e5 = *(const float2*)(eg + 5120 + j);
      float2 pc2 = {0.f, 0.f};
      if (p >= 0) pc2 = *(const float2*)(g_c + (size_t)p * 1024 + j);

      float cv[2], hf[2];
      #pragma unroll
      for (int e = 0; e < 2; ++e) {
        const float proj = ((e == 0) ? p0.x : p0.y) + ((e == 0) ? e0v.x : e0v.y);
        const float vi = ((e == 0) ? g0.x : g0.y) + ((e == 0) ? p1.x : p1.y) + ((e == 0) ? e1.x : e1.y);
        const float vo = ((e == 0) ? g1.x : g1.y) + ((e == 0) ? p2.x : p2.y) + ((e == 0) ? e2.x : e2.y);
        const float vf = ((e == 0) ? g2.x : g2.y) + ((e == 0) ? p3.x : p3.y) + ((e == 0) ? e3.x : e3.y);
        const float vu = ((e == 0) ? g3.x : g3.y) + ((e == 0) ? p4.x : p4.y) + ((e == 0) ? e4.x : e4.y);
        const float vr = ((e == 0) ? g4.x : g4.y) + ((e == 0) ? p5.x : p5.y) + ((e == 0) ? e5.x : e5.y);
        const float ig = 1.f / (1.f + expf(-vi));
        const float og = 1.f / (1.f + expf(-vo));
        const float fg = 1.f / (1.f + expf(-vf));
        const float rg = 1.f / (1.f + expf(-vr));
        const float ug = tanhf(vu);
        const float pc = (e == 0) ? pc2.x : pc2.y;
        const float c = ig * ug + fg * pc;
        const float h = og * tanhf(c);
        cv[e] = c;
        hf[e] = rg * h + (1.f - rg) * proj;
      }
      AST_F(&g_c[(size_t)node * 1024 + j], cv[0]);
      AST_F(&g_c[(size_t)node * 1024 + j + 1], cv[1]);
      unsigned short h0, l0, h1, l1;
      split2(hf[0], h0, l0);
      split2(hf[1], h1, l1);
      const unsigned hpk = (unsigned)h0 | ((unsigned)h1 << 16);
      const unsigned lpk = (unsigned)l0 | ((unsigned)l1 << 16);
      const size_t soff = sbase + (size_t)(j >> 3) * 128 + ((j & 7) >> 1);
      AST_U(&g_Spk_hi[soff], hpk);
      AST_U(&g_Spk_lo[soff], lpk);
      for (int ci = cs; ci < ce; ++ci) {
        const int prc = g_prow[g_clist[ci]];
        const size_t aoff = (size_t)(prc >> 5) * 16384 + (size_t)(j >> 3) * 128
                          + (size_t)(prc & 31) * 4 + ((j & 7) >> 1);
        AST_U(&g_Apk_hi[aoff], hpk);
        AST_U(&g_Apk_lo[aoff], lpk);
      }
    }
    gbar(&gen);
  }

  // -------- final level: dist + commits --------
  {
    const int Lf = nl - 1;
    const int s0f = g_lvl_start[Lf];
    const int Mf = g_lvl_start[Lf + 1] - s0f;
    const int nmtf = (Mf + 31) >> 5;
    const int Df = nmtf * 5;
    if (bid < Df) {
      dist_tile(Lf, bid / 5, bid % 5, bout, out, tid, w, l, lk, lj, smem, sdist);
    }
    gbar(&gen);
    for (int ni = bid; ni < Mf; ni += NBLK) {
      const int pn = g_order[s0f + ni];
      if (pn >= 8 && tid == 0)
        out[OUT_COMMIT_OFF + pn - 8] = (float)pamax_combine(g_prow[pn]);
    }
  }
}

extern "C" void kernel_launch(void* const* d_in, const int* in_sizes, int n_in,
                              void* d_out, int out_size, void* d_ws, size_t ws_size,
                              hipStream_t stream) {
  const float* feat   = (const float*)d_in[0];
  const int*   parent = (const int*)d_in[1];
  // d_in[2] = batch_size (8), hardcoded
  const float* Wpx  = (const float*)d_in[3];
  const float* bpx  = (const float*)d_in[4];
  const float* Wix  = (const float*)d_in[5];
  const float* bix  = (const float*)d_in[6];
  const float* Wih  = (const float*)d_in[7];
  const float* bih  = (const float*)d_in[8];
  const float* Wout = (const float*)d_in[9];
  const float* bout = (const float*)d_in[10];
  const float* emb  = (const float*)d_in[11];
  float* out = (float*)d_out;

  hipLaunchKernelGGL(prep_kernel, dim3(1), dim3(1024), 0, stream, parent, emb, out);
  hipLaunchKernelGGL(pack_all, dim3(2048), dim3(256), 0, stream, Wpx, Wix, Wih, feat, Wout);
  hipLaunchKernelGGL(emb_gemm, dim3(240), dim3(512), 0, stream, Wpx, Wix, bpx, bix, bih);
  hipLaunchKernelGGL(pre_gemm_mfma, dim3(768), dim3(256), 0, stream);
  hipLaunchKernelGGL(lstm_main, dim3(NBLK), dim3(NTHR), 0, stream,
                     parent, bout, out);
}